// Round 6
// baseline (484.724 us; speedup 1.0000x reference)
//
#include <hip/hip_runtime.h>
#include <hip/hip_bf16.h>

// Problem constants
#define B_ 4
#define DIM_ 256
#define N_ 2048
#define M_ 2048
#define HEADS_ 8
#define DHEAD_ 64
#define DINNER_ 512

typedef __attribute__((ext_vector_type(8))) short short8;
typedef __attribute__((ext_vector_type(4))) short short4v;
typedef __attribute__((ext_vector_type(4))) float floatx4;

__device__ inline short bf16r(float x) {  // RNE f32->bf16 (bit form)
  unsigned u = __float_as_uint(x);
  unsigned r = (u + 0x7fffu + ((u >> 16) & 1u)) >> 16;
  return (short)r;
}
__device__ inline float bf2f(short b) {
  return __uint_as_float(((unsigned)(unsigned short)b) << 16);
}

// ---------------------------------------------------------------------------
// Kernel 0: one-shot W split: whi/wlo bf16 planes of (W * gamma).
// grid (256, 3): y=0 Wq[512x256]*gamma, y=1 Wkv[1024x256]*gamma_ctx,
// y=2 Wout[256x512] (no gamma).  Each thread: one float4 group.
// ---------------------------------------------------------------------------
__global__ __launch_bounds__(256) void wsplit_kernel(
    const float* __restrict__ Wq, const float* __restrict__ Wkv,
    const float* __restrict__ Wout, const float* __restrict__ gamma,
    const float* __restrict__ gctx, short* __restrict__ whi,
    short* __restrict__ wlo) {
  const int y = blockIdx.y;
  const int gsz[3] = {32768, 65536, 32768};  // float4 groups per matrix
  const int goff[3] = {0, 131072, 393216};   // element offset in planes
  int gidx = blockIdx.x * 256 + threadIdx.x;
  if (gidx >= gsz[y]) return;
  const float* W = (y == 0) ? Wq : (y == 1) ? Wkv : Wout;
  const int cmask = (y == 2) ? 511 : 255;
  int e0 = gidx * 4;
  int c = e0 & cmask;
  float4 wv = *(const float4*)&W[e0];
  if (y < 2) {
    const float* g = (y == 0) ? gamma : gctx;
    float4 g4 = *(const float4*)&g[c];
    wv.x *= g4.x; wv.y *= g4.y; wv.z *= g4.z; wv.w *= g4.w;
  }
  float vv[4] = {wv.x, wv.y, wv.z, wv.w};
  short4v hi, lo;
#pragma unroll
  for (int e = 0; e < 4; ++e) {
    short hb = bf16r(vv[e]);
    hi[e] = hb;
    lo[e] = bf16r(vv[e] - bf2f(hb));
  }
  *(short4v*)&whi[goff[y] + e0] = hi;
  *(short4v*)&wlo[goff[y] + e0] = lo;
}

// ---------------------------------------------------------------------------
// Kernel 1: channel RMSNorm -> bf16 transposed, coalesced via LDS transpose.
// x:[b,256,NN] fp32 -> xt[b,n,256] bf16 (gamma folded into W elsewhere).
// grid (NN/64, B), block (64,4).
// ---------------------------------------------------------------------------
__global__ __launch_bounds__(256) void colnorm_t_kernel(
    const float* __restrict__ x, short* __restrict__ xt, int NN) {
  int b = blockIdx.y;
  int tx = threadIdx.x, ty = threadIdx.y;
  int n0 = blockIdx.x * 64, n = n0 + tx;
  const float* xb = x + (size_t)b * 256 * NN;

  float ssq = 0.f;
  for (int c = ty; c < 256; c += 4) {
    float v = xb[(size_t)c * NN + n];
    ssq += v * v;
  }
  __shared__ float red[4][64];
  __shared__ float scl[64];
  __shared__ float t[64][65];
  red[ty][tx] = ssq;
  __syncthreads();
  if (ty == 0) {
    float s = red[0][tx] + red[1][tx] + red[2][tx] + red[3][tx];
    scl[tx] = 16.0f / fmaxf(sqrtf(s), 1e-12f);
  }
  int tid = ty * 64 + tx;
  int row = tid >> 2, cg = tid & 3;
  for (int c0 = 0; c0 < 256; c0 += 64) {
    __syncthreads();
    for (int cc = ty; cc < 64; cc += 4) t[cc][tx] = xb[(size_t)(c0 + cc) * NN + n];
    __syncthreads();
    float sc = scl[row];
    short8 o0v, o1v;
#pragma unroll
    for (int e = 0; e < 8; ++e) {
      o0v[e] = bf16r(t[cg * 16 + e][row] * sc);
      o1v[e] = bf16r(t[cg * 16 + 8 + e][row] * sc);
    }
    size_t base = ((size_t)b * NN + n0 + row) * 256 + c0 + cg * 16;
    *(short8*)&xt[base] = o0v;
    *(short8*)&xt[base + 8] = o1v;
  }
}

// ---------------------------------------------------------------------------
// Kernel 2: MFMA GEMM from pre-split bf16 W planes.
// Y[b,o,n] = sum_c W'[o,c] * Xt[b,n,c], W' = whi + wlo (2 MFMAs ~ fp32 W).
// Block tile 128o x 128n, 4 waves 2x2, wave 64x64.
// ---------------------------------------------------------------------------
template <int EPI>
__global__ __launch_bounds__(256) void gemm_mfma_kernel(
    const short* __restrict__ whi, const short* __restrict__ wlo,
    const short* __restrict__ Xt, float* __restrict__ Yf,
    short* __restrict__ Yt, short* __restrict__ Yv, int C, int O) {
  const int b = blockIdx.z;
  const int n0 = blockIdx.x * 128;
  const int o0 = blockIdx.y * 128;
  const int tid = threadIdx.x;
  const int w = tid >> 6, l = tid & 63, quad = l >> 4, l15 = l & 15;
  const int wo = (w >> 1) * 64, wn = (w & 1) * 64;

  __shared__ __align__(16) short Wa[2][128][40];
  __shared__ __align__(16) short Xb[128][40];

  floatx4 acc[4][4];
#pragma unroll
  for (int ot = 0; ot < 4; ++ot)
#pragma unroll
    for (int nt = 0; nt < 4; ++nt)
#pragma unroll
      for (int r = 0; r < 4; ++r) acc[ot][nt][r] = 0.f;

  for (int c0 = 0; c0 < C; c0 += 32) {
    __syncthreads();
#pragma unroll
    for (int it = 0; it < 2; ++it) {
      int lin = tid + it * 256;
      int row = lin >> 2, sg = (lin & 3) * 8;
      size_t src = (size_t)(o0 + row) * C + c0 + sg;
      *(short8*)&Wa[0][row][sg] = *(const short8*)&whi[src];
      *(short8*)&Wa[1][row][sg] = *(const short8*)&wlo[src];
    }
#pragma unroll
    for (int it = 0; it < 2; ++it) {
      int lin = tid + it * 256;
      int nn = lin >> 2, sg = (lin & 3) * 8;
      *(short8*)&Xb[nn][sg] =
          *(const short8*)&Xt[((size_t)b * 2048 + n0 + nn) * C + c0 + sg];
    }
    __syncthreads();

    short8 ah[4], al[4], bx[4];
#pragma unroll
    for (int ot = 0; ot < 4; ++ot) {
      ah[ot] = *(const short8*)&Wa[0][wo + 16 * ot + l15][8 * quad];
      al[ot] = *(const short8*)&Wa[1][wo + 16 * ot + l15][8 * quad];
    }
#pragma unroll
    for (int nt = 0; nt < 4; ++nt)
      bx[nt] = *(const short8*)&Xb[wn + 16 * nt + l15][8 * quad];
#pragma unroll
    for (int ot = 0; ot < 4; ++ot)
#pragma unroll
      for (int nt = 0; nt < 4; ++nt) {
        acc[ot][nt] =
            __builtin_amdgcn_mfma_f32_16x16x32_bf16(al[ot], bx[nt], acc[ot][nt], 0, 0, 0);
        acc[ot][nt] =
            __builtin_amdgcn_mfma_f32_16x16x32_bf16(ah[ot], bx[nt], acc[ot][nt], 0, 0, 0);
      }
  }

  if (EPI == 0) {
#pragma unroll
    for (int ot = 0; ot < 4; ++ot)
#pragma unroll
      for (int r = 0; r < 4; ++r) {
        int o = o0 + wo + 16 * ot + 4 * quad + r;
#pragma unroll
        for (int nt = 0; nt < 4; ++nt)
          Yf[((size_t)b * O + o) * 2048 + n0 + wn + 16 * nt + l15] =
              acc[ot][nt][r];
      }
  } else if (EPI == 1 || (EPI == 2 && o0 < 512)) {
#pragma unroll
    for (int nt = 0; nt < 4; ++nt) {
      int n = n0 + wn + 16 * nt + l15;
      size_t base = ((size_t)b * 2048 + n) * 512;
#pragma unroll
      for (int ot = 0; ot < 4; ++ot) {
        int o = o0 + wo + 16 * ot + 4 * quad;
        short4v pk;
#pragma unroll
        for (int r = 0; r < 4; ++r) pk[r] = bf16r(acc[ot][nt][r]);
        *(short4v*)&Yt[base + o] = pk;
      }
    }
  } else {
#pragma unroll
    for (int ot = 0; ot < 4; ++ot)
#pragma unroll
      for (int r = 0; r < 4; ++r) {
        int ch = o0 - 512 + wo + 16 * ot + 4 * quad + r;
#pragma unroll
        for (int nt = 0; nt < 4; ++nt)
          Yv[((size_t)b * 512 + ch) * 2048 + n0 + wn + 16 * nt + l15] =
              bf16r(acc[ot][nt][r]);
      }
  }
}

// ---------------------------------------------------------------------------
// Kernel 3: k2m[(b*8+h)*M+m] = mask ? sum_d k~[m][h*64+d]^2 : +INF
// ---------------------------------------------------------------------------
__global__ __launch_bounds__(256) void k2_kernel(const short* __restrict__ kbT,
                                                 const int* __restrict__ mask,
                                                 float* __restrict__ k2m) {
  int w = threadIdx.x >> 6, l = threadIdx.x & 63;
  int row = blockIdx.x * 4 + w;  // row in [0, B*M)
  int b = row >> 11, m = row & 2047;
  short8 v = *(const short8*)&kbT[(size_t)row * 512 + 8 * l];
  float s = 0.f;
#pragma unroll
  for (int e = 0; e < 8; ++e) {
    float f = bf2f(v[e]);
    s += f * f;
  }
  s += __shfl_xor(s, 1);
  s += __shfl_xor(s, 2);
  s += __shfl_xor(s, 4);
  int mv = mask[row];
  if ((l & 7) == 0) {
    int h = l >> 3;
    k2m[((size_t)b * 8 + h) * 2048 + m] = mv ? s : __builtin_inff();
  }
}

// ---------------------------------------------------------------------------
// Kernel 4: L2-distance flash attention, max=0 softmax, wave-level j-split.
// Block 256 = 4 waves: jh = w&1 picks j-half, iw = w>>1 picks 16-row subtile.
// Block covers 32 q-rows; grid 2048 (64 i-blk x 32 bh, XCD-swizzled).
// 8 blocks/CU -> 32 waves/CU (needs VGPR<=64: launch_bounds(256,8)).
// Combine of j-halves = plain add through LDS (max==0, no rescale).
// ---------------------------------------------------------------------------
__global__ __launch_bounds__(256, 8) void attn_kernel(
    const short* __restrict__ qb, const short* __restrict__ kbT,
    const short* __restrict__ vb, const float* __restrict__ k2m,
    short* __restrict__ attn_t) {
  const int bid = blockIdx.x;
  const int rr = bid & 7, qq = bid >> 3;       // rr ~ XCD
  const int iblk = qq >> 2;                    // [0,64)
  const int g = rr * 4 + (qq & 3);             // bh in [0,32): 4 bh per XCD
  const int h = g & 7, b = g >> 3;
  const int i0 = iblk * 32;

  const int tid = threadIdx.x;
  const int w = tid >> 6, l = tid & 63, quad = l >> 4, l15 = l & 15;
  const int jh = w & 1, iw = w >> 1;

  __shared__ __align__(16) short p_s[2][32][72];
  __shared__ float o_lds[32][68];
  __shared__ float l_lds[32];

  const short* qrow = qb + ((size_t)b * N_ + i0 + 16 * iw + l15) * 512 + h * 64;
  const short* kbase = kbT + (size_t)b * M_ * 512 + h * 64;
  const short* vbase = vb + ((size_t)b * 512 + h * 64) * (size_t)M_;
  const float* k2b = k2m + ((size_t)b * 8 + h) * M_;

  short8 qa[2];
  float q2p = 0.f;
#pragma unroll
  for (int kt = 0; kt < 2; ++kt) {
    qa[kt] = *(const short8*)&qrow[32 * kt + 8 * quad];
#pragma unroll
    for (int jj = 0; jj < 8; ++jj) {
      float f = bf2f(qa[kt][jj]);
      q2p += f * f;
    }
  }
  float q2row = q2p + __shfl_xor(q2p, 16);
  q2row += __shfl_xor(q2row, 32);
  float q2c[4];
#pragma unroll
  for (int r = 0; r < 4; ++r) q2c[r] = __shfl(q2row, 4 * quad + r);

  floatx4 accO[4];
#pragma unroll
  for (int dt = 0; dt < 4; ++dt)
#pragma unroll
    for (int r = 0; r < 4; ++r) accO[dt][r] = 0.f;
  float lsum[4] = {0.f, 0.f, 0.f, 0.f};

  const int jbeg = jh * 1024;
  const float C2 = -0.18033688011112042f;  // -0.125 * log2(e)

  for (int j0 = jbeg; j0 < jbeg + 1024; j0 += 64) {
    // hoist k2 loads so their L2 latency overlaps the QK MFMAs
    float k2v[4];
#pragma unroll
    for (int jt = 0; jt < 4; ++jt) k2v[jt] = k2b[j0 + 16 * jt + l15];

    // ---- S = QK^T per 16-col tile; p = exp2(C2*dist); store bf16-trunc ----
#pragma unroll
    for (int jt = 0; jt < 4; ++jt) {
      const short* krow = kbase + (size_t)(j0 + 16 * jt + l15) * 512;
      short8 k0 = *(const short8*)&krow[8 * quad];
      short8 k1 = *(const short8*)&krow[32 + 8 * quad];
      floatx4 a;
#pragma unroll
      for (int r = 0; r < 4; ++r) a[r] = 0.f;
      a = __builtin_amdgcn_mfma_f32_16x16x32_bf16(qa[0], k0, a, 0, 0, 0);
      a = __builtin_amdgcn_mfma_f32_16x16x32_bf16(qa[1], k1, a, 0, 0, 0);
#pragma unroll
      for (int r = 0; r < 4; ++r) {
        // max(max(x,0),eps) == max(x,eps)
        float d2 = fmaxf(fmaf(-2.f, a[r], q2c[r] + k2v[jt]), 1e-12f);
        float p = __builtin_amdgcn_exp2f(C2 * __builtin_amdgcn_sqrtf(d2));
        unsigned u = __float_as_uint(p);
        lsum[r] += __uint_as_float(u & 0xffff0000u);  // l consistent with P-hat
        p_s[jh][16 * iw + 4 * quad + r][16 * jt + l15] = (short)(u >> 16);
      }
    }

    // ---- O += P V (p_s rows wave-private via (jh,iw); no barrier) ----
    short8 pa0 = *(const short8*)&p_s[jh][16 * iw + l15][8 * quad];
    short8 pa1 = *(const short8*)&p_s[jh][16 * iw + l15][32 + 8 * quad];
#pragma unroll
    for (int dt = 0; dt < 4; ++dt) {
      const short* vrow = vbase + (size_t)(16 * dt + l15) * M_ + j0;
      short8 vf0 = *(const short8*)&vrow[8 * quad];
      short8 vf1 = *(const short8*)&vrow[32 + 8 * quad];
      accO[dt] =
          __builtin_amdgcn_mfma_f32_16x16x32_bf16(pa0, vf0, accO[dt], 0, 0, 0);
      accO[dt] =
          __builtin_amdgcn_mfma_f32_16x16x32_bf16(pa1, vf1, accO[dt], 0, 0, 0);
    }
  }

  // ---- reduce l over the 16-lane column groups (once) ----
#pragma unroll
  for (int off = 1; off < 16; off <<= 1)
#pragma unroll
    for (int r = 0; r < 4; ++r) lsum[r] += __shfl_xor(lsum[r], off);

  // ---- combine the two j-halves (plain add; max==0 softmax) ----
  if (jh == 1) {
#pragma unroll
    for (int dt = 0; dt < 4; ++dt)
#pragma unroll
      for (int r = 0; r < 4; ++r)
        o_lds[16 * iw + 4 * quad + r][16 * dt + l15] = accO[dt][r];
    if (l15 == 0) {
#pragma unroll
      for (int r = 0; r < 4; ++r) l_lds[16 * iw + 4 * quad + r] = lsum[r];
    }
  }
  __syncthreads();
  if (jh == 0) {
#pragma unroll
    for (int r = 0; r < 4; ++r) {
      int row = 16 * iw + 4 * quad + r;
      float lt = lsum[r] + l_lds[row];
      float rl = 1.0f / lt;
      size_t base = ((size_t)b * N_ + i0 + row) * 512 + h * 64;
#pragma unroll
      for (int dt = 0; dt < 4; ++dt) {
        float o = accO[dt][r] + o_lds[row][16 * dt + l15];
        attn_t[base + 16 * dt + l15] = bf16r(o * rl);
      }
    }
  }
}

// ---------------------------------------------------------------------------
extern "C" void kernel_launch(void* const* d_in, const int* in_sizes, int n_in,
                              void* d_out, int out_size, void* d_ws,
                              size_t ws_size, hipStream_t stream) {
  const float* fmap = (const float*)d_in[0];
  const float* context = (const float*)d_in[1];
  const int* mask = (const int*)d_in[2];
  const float* gamma = (const float*)d_in[3];
  const float* gamma_ctx = (const float*)d_in[4];
  const float* Wq = (const float*)d_in[5];
  const float* Wkv = (const float*)d_in[6];
  const float* Wout = (const float*)d_in[7];
  float* out = (float*)d_out;

  char* ws = (char*)d_ws;
  short* fmap_t = (short*)ws;                 // 4 MB
  short* ctx_t = fmap_t + 2097152;            // 4 MB
  short* qb = ctx_t + 2097152;                // 8 MB
  short* kbT = qb + 4194304;                  // 8 MB
  short* vb = kbT + 4194304;                  // 8 MB
  short* attn_t = vb + 4194304;               // 8 MB
  float* k2m = (float*)(attn_t + 4194304);    // 256 KB
  short* whi = (short*)(k2m + 65536);         // 1 MB
  short* wlo = whi + 524288;                  // 1 MB

  dim3 blk64x4(64, 4);
  wsplit_kernel<<<dim3(256, 3), 256, 0, stream>>>(Wq, Wkv, Wout, gamma,
                                                  gamma_ctx, whi, wlo);
  colnorm_t_kernel<<<dim3(N_ / 64, B_), blk64x4, 0, stream>>>(fmap, fmap_t, N_);
  colnorm_t_kernel<<<dim3(M_ / 64, B_), blk64x4, 0, stream>>>(context, ctx_t,
                                                              M_);
  gemm_mfma_kernel<1><<<dim3(16, 4, B_), 256, 0, stream>>>(
      whi, wlo, fmap_t, nullptr, qb, nullptr, DIM_, DINNER_);
  gemm_mfma_kernel<2><<<dim3(16, 8, B_), 256, 0, stream>>>(
      whi + 131072, wlo + 131072, ctx_t, nullptr, kbT, vb, DIM_, 2 * DINNER_);
  k2_kernel<<<dim3(B_ * M_ / 4), 256, 0, stream>>>(kbT, mask, k2m);
  attn_kernel<<<dim3(2048), 256, 0, stream>>>(qb, kbT, vb, k2m, attn_t);
  gemm_mfma_kernel<0><<<dim3(16, 2, B_), 256, 0, stream>>>(
      whi + 393216, wlo + 393216, attn_t, out, nullptr, nullptr, DINNER_,
      DIM_);
}

// Round 7
// 409.038 us; speedup vs baseline: 1.1850x; 1.1850x over previous
//
#include <hip/hip_runtime.h>
#include <hip/hip_bf16.h>

// Problem constants
#define B_ 4
#define DIM_ 256
#define N_ 2048
#define M_ 2048
#define HEADS_ 8
#define DHEAD_ 64
#define DINNER_ 512

typedef __attribute__((ext_vector_type(8))) short short8;
typedef __attribute__((ext_vector_type(4))) short short4v;
typedef __attribute__((ext_vector_type(4))) float floatx4;

__device__ inline short bf16r(float x) {  // RNE f32->bf16 (bit form)
  unsigned u = __float_as_uint(x);
  unsigned r = (u + 0x7fffu + ((u >> 16) & 1u)) >> 16;
  return (short)r;
}
__device__ inline float bf2f(short b) {
  return __uint_as_float(((unsigned)(unsigned short)b) << 16);
}

// ---------------------------------------------------------------------------
// Kernel 0: one-shot W split: whi/wlo bf16 planes of (W * gamma).
// grid (256, 3): y=0 Wq[512x256]*gamma, y=1 Wkv[1024x256]*gamma_ctx,
// y=2 Wout[256x512] (no gamma).  Each thread: one float4 group.
// ---------------------------------------------------------------------------
__global__ __launch_bounds__(256) void wsplit_kernel(
    const float* __restrict__ Wq, const float* __restrict__ Wkv,
    const float* __restrict__ Wout, const float* __restrict__ gamma,
    const float* __restrict__ gctx, short* __restrict__ whi,
    short* __restrict__ wlo) {
  const int y = blockIdx.y;
  const int gsz[3] = {32768, 65536, 32768};  // float4 groups per matrix
  const int goff[3] = {0, 131072, 393216};   // element offset in planes
  int gidx = blockIdx.x * 256 + threadIdx.x;
  if (gidx >= gsz[y]) return;
  const float* W = (y == 0) ? Wq : (y == 1) ? Wkv : Wout;
  const int cmask = (y == 2) ? 511 : 255;
  int e0 = gidx * 4;
  int c = e0 & cmask;
  float4 wv = *(const float4*)&W[e0];
  if (y < 2) {
    const float* g = (y == 0) ? gamma : gctx;
    float4 g4 = *(const float4*)&g[c];
    wv.x *= g4.x; wv.y *= g4.y; wv.z *= g4.z; wv.w *= g4.w;
  }
  float vv[4] = {wv.x, wv.y, wv.z, wv.w};
  short4v hi, lo;
#pragma unroll
  for (int e = 0; e < 4; ++e) {
    short hb = bf16r(vv[e]);
    hi[e] = hb;
    lo[e] = bf16r(vv[e] - bf2f(hb));
  }
  *(short4v*)&whi[goff[y] + e0] = hi;
  *(short4v*)&wlo[goff[y] + e0] = lo;
}

// ---------------------------------------------------------------------------
// Kernel 1: channel RMSNorm -> bf16 transposed, coalesced via LDS transpose.
// x:[b,256,NN] fp32 -> xt[b,n,256] bf16 (gamma folded into W elsewhere).
// grid (NN/64, B), block (64,4).
// ---------------------------------------------------------------------------
__global__ __launch_bounds__(256) void colnorm_t_kernel(
    const float* __restrict__ x, short* __restrict__ xt, int NN) {
  int b = blockIdx.y;
  int tx = threadIdx.x, ty = threadIdx.y;
  int n0 = blockIdx.x * 64, n = n0 + tx;
  const float* xb = x + (size_t)b * 256 * NN;

  float ssq = 0.f;
  for (int c = ty; c < 256; c += 4) {
    float v = xb[(size_t)c * NN + n];
    ssq += v * v;
  }
  __shared__ float red[4][64];
  __shared__ float scl[64];
  __shared__ float t[64][65];
  red[ty][tx] = ssq;
  __syncthreads();
  if (ty == 0) {
    float s = red[0][tx] + red[1][tx] + red[2][tx] + red[3][tx];
    scl[tx] = 16.0f / fmaxf(sqrtf(s), 1e-12f);
  }
  int tid = ty * 64 + tx;
  int row = tid >> 2, cg = tid & 3;
  for (int c0 = 0; c0 < 256; c0 += 64) {
    __syncthreads();
    for (int cc = ty; cc < 64; cc += 4) t[cc][tx] = xb[(size_t)(c0 + cc) * NN + n];
    __syncthreads();
    float sc = scl[row];
    short8 o0v, o1v;
#pragma unroll
    for (int e = 0; e < 8; ++e) {
      o0v[e] = bf16r(t[cg * 16 + e][row] * sc);
      o1v[e] = bf16r(t[cg * 16 + 8 + e][row] * sc);
    }
    size_t base = ((size_t)b * NN + n0 + row) * 256 + c0 + cg * 16;
    *(short8*)&xt[base] = o0v;
    *(short8*)&xt[base + 8] = o1v;
  }
}

// ---------------------------------------------------------------------------
// Kernel 2: MFMA GEMM from pre-split bf16 W planes.
// Y[b,o,n] = sum_c W'[o,c] * Xt[b,n,c], W' = whi + wlo (2 MFMAs ~ fp32 W).
// Block tile 128o x 128n, 4 waves 2x2, wave 64x64.
// ---------------------------------------------------------------------------
template <int EPI>
__global__ __launch_bounds__(256) void gemm_mfma_kernel(
    const short* __restrict__ whi, const short* __restrict__ wlo,
    const short* __restrict__ Xt, float* __restrict__ Yf,
    short* __restrict__ Yt, short* __restrict__ Yv, int C, int O) {
  const int b = blockIdx.z;
  const int n0 = blockIdx.x * 128;
  const int o0 = blockIdx.y * 128;
  const int tid = threadIdx.x;
  const int w = tid >> 6, l = tid & 63, quad = l >> 4, l15 = l & 15;
  const int wo = (w >> 1) * 64, wn = (w & 1) * 64;

  __shared__ __align__(16) short Wa[2][128][40];
  __shared__ __align__(16) short Xb[128][40];

  floatx4 acc[4][4];
#pragma unroll
  for (int ot = 0; ot < 4; ++ot)
#pragma unroll
    for (int nt = 0; nt < 4; ++nt)
#pragma unroll
      for (int r = 0; r < 4; ++r) acc[ot][nt][r] = 0.f;

  for (int c0 = 0; c0 < C; c0 += 32) {
    __syncthreads();
#pragma unroll
    for (int it = 0; it < 2; ++it) {
      int lin = tid + it * 256;
      int row = lin >> 2, sg = (lin & 3) * 8;
      size_t src = (size_t)(o0 + row) * C + c0 + sg;
      *(short8*)&Wa[0][row][sg] = *(const short8*)&whi[src];
      *(short8*)&Wa[1][row][sg] = *(const short8*)&wlo[src];
    }
#pragma unroll
    for (int it = 0; it < 2; ++it) {
      int lin = tid + it * 256;
      int nn = lin >> 2, sg = (lin & 3) * 8;
      *(short8*)&Xb[nn][sg] =
          *(const short8*)&Xt[((size_t)b * 2048 + n0 + nn) * C + c0 + sg];
    }
    __syncthreads();

    short8 ah[4], al[4], bx[4];
#pragma unroll
    for (int ot = 0; ot < 4; ++ot) {
      ah[ot] = *(const short8*)&Wa[0][wo + 16 * ot + l15][8 * quad];
      al[ot] = *(const short8*)&Wa[1][wo + 16 * ot + l15][8 * quad];
    }
#pragma unroll
    for (int nt = 0; nt < 4; ++nt)
      bx[nt] = *(const short8*)&Xb[wn + 16 * nt + l15][8 * quad];
#pragma unroll
    for (int ot = 0; ot < 4; ++ot)
#pragma unroll
      for (int nt = 0; nt < 4; ++nt) {
        acc[ot][nt] =
            __builtin_amdgcn_mfma_f32_16x16x32_bf16(al[ot], bx[nt], acc[ot][nt], 0, 0, 0);
        acc[ot][nt] =
            __builtin_amdgcn_mfma_f32_16x16x32_bf16(ah[ot], bx[nt], acc[ot][nt], 0, 0, 0);
      }
  }

  if (EPI == 0) {
#pragma unroll
    for (int ot = 0; ot < 4; ++ot)
#pragma unroll
      for (int r = 0; r < 4; ++r) {
        int o = o0 + wo + 16 * ot + 4 * quad + r;
#pragma unroll
        for (int nt = 0; nt < 4; ++nt)
          Yf[((size_t)b * O + o) * 2048 + n0 + wn + 16 * nt + l15] =
              acc[ot][nt][r];
      }
  } else if (EPI == 1 || (EPI == 2 && o0 < 512)) {
#pragma unroll
    for (int nt = 0; nt < 4; ++nt) {
      int n = n0 + wn + 16 * nt + l15;
      size_t base = ((size_t)b * 2048 + n) * 512;
#pragma unroll
      for (int ot = 0; ot < 4; ++ot) {
        int o = o0 + wo + 16 * ot + 4 * quad;
        short4v pk;
#pragma unroll
        for (int r = 0; r < 4; ++r) pk[r] = bf16r(acc[ot][nt][r]);
        *(short4v*)&Yt[base + o] = pk;
      }
    }
  } else {
#pragma unroll
    for (int ot = 0; ot < 4; ++ot)
#pragma unroll
      for (int r = 0; r < 4; ++r) {
        int ch = o0 - 512 + wo + 16 * ot + 4 * quad + r;
#pragma unroll
        for (int nt = 0; nt < 4; ++nt)
          Yv[((size_t)b * 512 + ch) * 2048 + n0 + wn + 16 * nt + l15] =
              bf16r(acc[ot][nt][r]);
      }
  }
}

// ---------------------------------------------------------------------------
// Kernel 3: k2m[(b*8+h)*M+m] = mask ? sum_d k~[m][h*64+d]^2 : +INF
// ---------------------------------------------------------------------------
__global__ __launch_bounds__(256) void k2_kernel(const short* __restrict__ kbT,
                                                 const int* __restrict__ mask,
                                                 float* __restrict__ k2m) {
  int w = threadIdx.x >> 6, l = threadIdx.x & 63;
  int row = blockIdx.x * 4 + w;  // row in [0, B*M)
  int b = row >> 11, m = row & 2047;
  short8 v = *(const short8*)&kbT[(size_t)row * 512 + 8 * l];
  float s = 0.f;
#pragma unroll
  for (int e = 0; e < 8; ++e) {
    float f = bf2f(v[e]);
    s += f * f;
  }
  s += __shfl_xor(s, 1);
  s += __shfl_xor(s, 2);
  s += __shfl_xor(s, 4);
  int mv = mask[row];
  if ((l & 7) == 0) {
    int h = l >> 3;
    k2m[((size_t)b * 8 + h) * 2048 + m] = mv ? s : __builtin_inff();
  }
}

// ---------------------------------------------------------------------------
// Kernel 4: L2-distance flash attention, max=0 softmax, wave-level j-split.
// Block 256 = 4 waves: jh = w&1 picks j-half, iw = w>>1 picks 16-row subtile.
// Block covers 32 q-rows; grid 2048 (64 i-blk x 32 bh, XCD-swizzled).
// launch_bounds (256,4): R5/R6 showed any tighter cap (->64 VGPR) forces
// accumulator spills (WRITE_SIZE 8MB -> 280MB).  Actual use ~56-64 VGPR
// still allows 8 waves/SIMD; LDS 18.4KB allows 8 blocks/CU.
// Combine of j-halves = plain add through LDS (max==0, no rescale).
// ---------------------------------------------------------------------------
__global__ __launch_bounds__(256, 4) void attn_kernel(
    const short* __restrict__ qb, const short* __restrict__ kbT,
    const short* __restrict__ vb, const float* __restrict__ k2m,
    short* __restrict__ attn_t) {
  const int bid = blockIdx.x;
  const int rr = bid & 7, qq = bid >> 3;       // rr ~ XCD
  const int iblk = qq >> 2;                    // [0,64)
  const int g = rr * 4 + (qq & 3);             // bh in [0,32): 4 bh per XCD
  const int h = g & 7, b = g >> 3;
  const int i0 = iblk * 32;

  const int tid = threadIdx.x;
  const int w = tid >> 6, l = tid & 63, quad = l >> 4, l15 = l & 15;
  const int jh = w & 1, iw = w >> 1;

  __shared__ __align__(16) short p_s[2][32][72];
  __shared__ float o_lds[32][68];
  __shared__ float l_lds[32];

  const short* qrow = qb + ((size_t)b * N_ + i0 + 16 * iw + l15) * 512 + h * 64;
  const short* kbase = kbT + (size_t)b * M_ * 512 + h * 64;
  const short* vbase = vb + ((size_t)b * 512 + h * 64) * (size_t)M_;
  const float* k2b = k2m + ((size_t)b * 8 + h) * M_;

  short8 qa[2];
  float q2p = 0.f;
#pragma unroll
  for (int kt = 0; kt < 2; ++kt) {
    qa[kt] = *(const short8*)&qrow[32 * kt + 8 * quad];
#pragma unroll
    for (int jj = 0; jj < 8; ++jj) {
      float f = bf2f(qa[kt][jj]);
      q2p += f * f;
    }
  }
  float q2row = q2p + __shfl_xor(q2p, 16);
  q2row += __shfl_xor(q2row, 32);
  float q2c[4];
#pragma unroll
  for (int r = 0; r < 4; ++r) q2c[r] = __shfl(q2row, 4 * quad + r);

  floatx4 accO[4];
#pragma unroll
  for (int dt = 0; dt < 4; ++dt)
#pragma unroll
    for (int r = 0; r < 4; ++r) accO[dt][r] = 0.f;
  float lsum[4] = {0.f, 0.f, 0.f, 0.f};

  const int jbeg = jh * 1024;
  const float C2 = -0.18033688011112042f;  // -0.125 * log2(e)

  for (int j0 = jbeg; j0 < jbeg + 1024; j0 += 64) {
    // hoist k2 loads so their L2 latency overlaps the QK MFMAs
    float k2v[4];
#pragma unroll
    for (int jt = 0; jt < 4; ++jt) k2v[jt] = k2b[j0 + 16 * jt + l15];

    // ---- S = QK^T per 16-col tile; p = exp2(C2*dist); store bf16-trunc ----
#pragma unroll
    for (int jt = 0; jt < 4; ++jt) {
      const short* krow = kbase + (size_t)(j0 + 16 * jt + l15) * 512;
      short8 k0 = *(const short8*)&krow[8 * quad];
      short8 k1 = *(const short8*)&krow[32 + 8 * quad];
      floatx4 a;
#pragma unroll
      for (int r = 0; r < 4; ++r) a[r] = 0.f;
      a = __builtin_amdgcn_mfma_f32_16x16x32_bf16(qa[0], k0, a, 0, 0, 0);
      a = __builtin_amdgcn_mfma_f32_16x16x32_bf16(qa[1], k1, a, 0, 0, 0);
#pragma unroll
      for (int r = 0; r < 4; ++r) {
        // max(max(x,0),eps) == max(x,eps)
        float d2 = fmaxf(fmaf(-2.f, a[r], q2c[r] + k2v[jt]), 1e-12f);
        float p = __builtin_amdgcn_exp2f(C2 * __builtin_amdgcn_sqrtf(d2));
        unsigned u = __float_as_uint(p);
        lsum[r] += __uint_as_float(u & 0xffff0000u);  // l consistent with P-hat
        p_s[jh][16 * iw + 4 * quad + r][16 * jt + l15] = (short)(u >> 16);
      }
    }

    // ---- O += P V (p_s rows wave-private via (jh,iw); no barrier) ----
    short8 pa0 = *(const short8*)&p_s[jh][16 * iw + l15][8 * quad];
    short8 pa1 = *(const short8*)&p_s[jh][16 * iw + l15][32 + 8 * quad];
#pragma unroll
    for (int dt = 0; dt < 4; ++dt) {
      const short* vrow = vbase + (size_t)(16 * dt + l15) * M_ + j0;
      short8 vf0 = *(const short8*)&vrow[8 * quad];
      short8 vf1 = *(const short8*)&vrow[32 + 8 * quad];
      accO[dt] =
          __builtin_amdgcn_mfma_f32_16x16x32_bf16(pa0, vf0, accO[dt], 0, 0, 0);
      accO[dt] =
          __builtin_amdgcn_mfma_f32_16x16x32_bf16(pa1, vf1, accO[dt], 0, 0, 0);
    }
  }

  // ---- reduce l over the 16-lane column groups (once) ----
#pragma unroll
  for (int off = 1; off < 16; off <<= 1)
#pragma unroll
    for (int r = 0; r < 4; ++r) lsum[r] += __shfl_xor(lsum[r], off);

  // ---- combine the two j-halves (plain add; max==0 softmax) ----
  if (jh == 1) {
#pragma unroll
    for (int dt = 0; dt < 4; ++dt)
#pragma unroll
      for (int r = 0; r < 4; ++r)
        o_lds[16 * iw + 4 * quad + r][16 * dt + l15] = accO[dt][r];
    if (l15 == 0) {
#pragma unroll
      for (int r = 0; r < 4; ++r) l_lds[16 * iw + 4 * quad + r] = lsum[r];
    }
  }
  __syncthreads();
  if (jh == 0) {
#pragma unroll
    for (int r = 0; r < 4; ++r) {
      int row = 16 * iw + 4 * quad + r;
      float lt = lsum[r] + l_lds[row];
      float rl = 1.0f / lt;
      size_t base = ((size_t)b * N_ + i0 + row) * 512 + h * 64;
#pragma unroll
      for (int dt = 0; dt < 4; ++dt) {
        float o = accO[dt][r] + o_lds[row][16 * dt + l15];
        attn_t[base + 16 * dt + l15] = bf16r(o * rl);
      }
    }
  }
}

// ---------------------------------------------------------------------------
extern "C" void kernel_launch(void* const* d_in, const int* in_sizes, int n_in,
                              void* d_out, int out_size, void* d_ws,
                              size_t ws_size, hipStream_t stream) {
  const float* fmap = (const float*)d_in[0];
  const float* context = (const float*)d_in[1];
  const int* mask = (const int*)d_in[2];
  const float* gamma = (const float*)d_in[3];
  const float* gamma_ctx = (const float*)d_in[4];
  const float* Wq = (const float*)d_in[5];
  const float* Wkv = (const float*)d_in[6];
  const float* Wout = (const float*)d_in[7];
  float* out = (float*)d_out;

  char* ws = (char*)d_ws;
  short* fmap_t = (short*)ws;                 // 4 MB
  short* ctx_t = fmap_t + 2097152;            // 4 MB
  short* qb = ctx_t + 2097152;                // 8 MB
  short* kbT = qb + 4194304;                  // 8 MB
  short* vb = kbT + 4194304;                  // 8 MB
  short* attn_t = vb + 4194304;               // 8 MB
  float* k2m = (float*)(attn_t + 4194304);    // 256 KB
  short* whi = (short*)(k2m + 65536);         // 1 MB
  short* wlo = whi + 524288;                  // 1 MB

  dim3 blk64x4(64, 4);
  wsplit_kernel<<<dim3(256, 3), 256, 0, stream>>>(Wq, Wkv, Wout, gamma,
                                                  gamma_ctx, whi, wlo);
  colnorm_t_kernel<<<dim3(N_ / 64, B_), blk64x4, 0, stream>>>(fmap, fmap_t, N_);
  colnorm_t_kernel<<<dim3(M_ / 64, B_), blk64x4, 0, stream>>>(context, ctx_t,
                                                              M_);
  gemm_mfma_kernel<1><<<dim3(16, 4, B_), 256, 0, stream>>>(
      whi, wlo, fmap_t, nullptr, qb, nullptr, DIM_, DINNER_);
  gemm_mfma_kernel<2><<<dim3(16, 8, B_), 256, 0, stream>>>(
      whi + 131072, wlo + 131072, ctx_t, nullptr, kbT, vb, DIM_, 2 * DINNER_);
  k2_kernel<<<dim3(B_ * M_ / 4), 256, 0, stream>>>(kbT, mask, k2m);
  attn_kernel<<<dim3(2048), 256, 0, stream>>>(qb, kbT, vb, k2m, attn_t);
  gemm_mfma_kernel<0><<<dim3(16, 2, B_), 256, 0, stream>>>(
      whi + 393216, wlo + 393216, attn_t, out, nullptr, nullptr, DINNER_,
      DIM_);
}